// Round 5
// baseline (209.011 us; speedup 1.0000x reference)
//
#include <hip/hip_runtime.h>

// RoiAlign fused: level-select + crop_and_resize(7x7 bilinear, extrap 0)
// feat0: [B,256,256,256] f32 NHWC ; feat1: [B,128,128,256] f32 ; rois: [B,R,5]
// out: [B,R,7,7,256] f32
//
// Mapping: ONE WAVE PER 4 POOL POSITIONS (13 waves/box; wave q handles
// p = 4q .. min(4q+3,48)). Lane -> 4 channels via float4. All 16 tap loads
// (4 positions x 4 taps, 16B/lane each) issue before any use -> max
// memory-level parallelism per wave; box math amortized 4x.
// A/B history: R3 block-per-box (CU locality) = 214.5us; R1 1 pos/wave =
// 207.4; R4 2 pos/wave = 208.9. Latency/BW-bound with ~145us fixed harness
// fill/restore cost in the timed window.
//
// NOTE: plain (cached) stores only. __builtin_nontemporal_store caused
// post-timing divergence (harness re-poisons d_out through the cached path;
// NT-stored lines get clobbered by later eviction of stale dirty poison
// lines). Do not reintroduce.

#define POOL 7
#define NCH 256
#define WPB 13   // waves per box

typedef float v4f __attribute__((ext_vector_type(4)));

__global__ __launch_bounds__(256) void roialign_kernel(
    const float* __restrict__ feat0,
    const float* __restrict__ feat1,
    const float* __restrict__ rois,
    float* __restrict__ out,
    int NB, int R) // NB = B*R
{
    int t = blockIdx.x * blockDim.x + threadIdx.x;
    int lane = t & 63;          // channel group: channels [4*lane .. 4*lane+3]
    int wid  = t >> 6;          // n*WPB + q
    int n    = wid / WPB;
    if (n >= NB) return;
    int q     = wid - n * WPB;
    int pbase = q * 4;
    int cnt   = 49 - pbase; if (cnt > 4) cnt = 4;  // q==12 -> 1 position

    const float* roi = rois + (size_t)n * 5;
    float y1 = roi[0], x1 = roi[1], y2 = roi[2], x2 = roi[3];

    // level select on RAW box coords, matching ref
    bool lvl = (y2 - y1 > 48.0f) || (x2 - x1 > 48.0f);
    const float* feat = lvl ? feat1 : feat0;
    int H = lvl ? 128 : 256;
    int W = H;
    int b = n / R;

    const float inv_img = 1.0f / 1024.0f;
    float y1n = y1 * inv_img, y2n = y2 * inv_img;
    float x1n = x1 * inv_img, x2n = x2 * inv_img;
    float Hm1 = (float)(H - 1), Wm1 = (float)(W - 1);
    float dy = y2n - y1n, dx = x2n - x1n;

    size_t plane = (size_t)b * H * W;
    int coff = lane * 4;
    float* outbase = out + (size_t)n * 49 * NCH + coff;

    float wyv[4], wxv[4];
    bool validv[4];
    const float* addr[4][4];

    #pragma unroll
    for (int k = 0; k < 4; ++k) {
        int p = pbase + k; if (p > 48) p = 48;   // clamped dup; store skipped
        int i = p / POOL, j = p - i * POOL;

        // same float op order as reference
        float ys = (y1n + ((float)i / 6.0f) * dy) * Hm1;
        float xs = (x1n + ((float)j / 6.0f) * dx) * Wm1;
        float y0f = floorf(ys), x0f = floorf(xs);
        wyv[k] = ys - y0f;
        wxv[k] = xs - x0f;
        int ya = (int)fminf(fmaxf(y0f,        0.0f), Hm1);
        int yb = (int)fminf(fmaxf(y0f + 1.0f, 0.0f), Hm1);
        int xa = (int)fminf(fmaxf(x0f,        0.0f), Wm1);
        int xb = (int)fminf(fmaxf(x0f + 1.0f, 0.0f), Wm1);
        validv[k] = (ys >= 0.0f) && (ys <= Hm1) && (xs >= 0.0f) && (xs <= Wm1);
        size_t r0 = (plane + (size_t)ya * W) * NCH;
        size_t r1 = (plane + (size_t)yb * W) * NCH;
        addr[k][0] = feat + r0 + (size_t)xa * NCH + coff;
        addr[k][1] = feat + r0 + (size_t)xb * NCH + coff;
        addr[k][2] = feat + r1 + (size_t)xa * NCH + coff;
        addr[k][3] = feat + r1 + (size_t)xb * NCH + coff;
    }

    // ---- 16 independent loads, all issued before first use ----
    v4f v[4][4];
    #pragma unroll
    for (int k = 0; k < 4; ++k)
        #pragma unroll
        for (int s = 0; s < 4; ++s)
            v[k][s] = *(const v4f*)addr[k][s];

    #pragma unroll
    for (int k = 0; k < 4; ++k) {
        if (k < cnt) {
            float wx = wxv[k], wy = wyv[k];
            float wxc = 1.0f - wx, wyc = 1.0f - wy;
            v4f top = v[k][0] * wxc + v[k][1] * wx;
            v4f bot = v[k][2] * wxc + v[k][3] * wx;
            v4f o   = top * wyc + bot * wy;
            if (!validv[k]) o = (v4f)0.0f;
            *(v4f*)(outbase + (size_t)(pbase + k) * NCH) = o;
        }
    }
}

extern "C" void kernel_launch(void* const* d_in, const int* in_sizes, int n_in,
                              void* d_out, int out_size, void* d_ws, size_t ws_size,
                              hipStream_t stream) {
    const float* feat0 = (const float*)d_in[0];
    const float* feat1 = (const float*)d_in[1];
    const float* rois  = (const float*)d_in[2];
    float* out = (float*)d_out;

    int B  = in_sizes[0] / (256 * 256 * 256); // feat0 = [B,256,256,256]
    int NB = in_sizes[2] / 5;                 // rois  = [B,R,5] -> B*R boxes
    int R  = NB / B;

    // WPB waves per box (4 pool positions per wave), 64 lanes each
    long long threads = (long long)NB * WPB * 64;
    int block = 256;
    int grid = (int)((threads + block - 1) / block);
    roialign_kernel<<<grid, block, 0, stream>>>(feat0, feat1, rois, out, NB, R);
}